// Round 11
// baseline (271.085 us; speedup 1.0000x reference)
//
#include <hip/hip_runtime.h>
#include <math.h>

#define IN_C 64
#define HID_C 128
#define OUT_C 64
#define NBK 256   // buckets of 512 nodes: bucket = dst >> 9
#define BD 64     // msplit bin ring depth
#define GS 16     // global atomic counter stride (ints) -> one 64B line each
// packed edge = (src<<9)|(dst&511); sentinel -1 unreachable (src <= N < 2^17).
// CSR rows padded to 8-multiples with dummy src = N (row N of xh/zh zeroed).
// Gathers: 8 lanes/node, unguarded padded inner loop, csr-index software
// pipeline (prefetch next chunk's 8 indices while processing current).

typedef __attribute__((ext_vector_type(8))) short bf16x8;   // 8 bf16 (4 VGPRs)
typedef __attribute__((ext_vector_type(4))) float f32x4;    // mfma C/D, NT-able
typedef __attribute__((ext_vector_type(4))) unsigned u32x4; // NT-able uint4

__device__ __forceinline__ unsigned short f2bf(float f) {
  unsigned u = __float_as_uint(f);
  u = (u + 0x7FFFu + ((u >> 16) & 1u)) >> 16;  // RNE
  return (unsigned short)u;
}
__device__ __forceinline__ float bf2f(unsigned v) {  // low 16 bits = bf16
  return __uint_as_float(v << 16);
}
__device__ __forceinline__ unsigned pack2(float a, float b) {
  return (unsigned)f2bf(a) | ((unsigned)f2bf(b) << 16);
}

// ==== fused: bhist (0..1023) + x->bf16 cast (1024..3071) + W pack (3072+) ====
__global__ __launch_bounds__(256) void k_xb(const int* __restrict__ dst,
                                            int* __restrict__ bh,
                                            const float4* __restrict__ x4,
                                            uint2* __restrict__ xh2,
                                            const float* __restrict__ W1l,
                                            const float* __restrict__ W1r,
                                            const float* __restrict__ W2l,
                                            const float* __restrict__ W2r,
                                            unsigned short* __restrict__ w1h,
                                            unsigned short* __restrict__ w2h,
                                            int E, int Mreal, int Mtot) {
  __shared__ int hh[NBK];
  int t = threadIdx.x;
  if (blockIdx.x < 1024) {
    hh[t] = 0;
    __syncthreads();
    for (int e = blockIdx.x * 256 + t; e < E; e += 1024 * 256)
      atomicAdd(&hh[dst[e] >> 9], 1);
    __syncthreads();
    if (hh[t]) atomicAdd(&bh[t * GS], hh[t]);
  } else if (blockIdx.x < 3072) {
    int b = blockIdx.x - 1024;
    for (int i = b * 256 + t; i < Mtot; i += 2048 * 256) {
      uint2 p = {0u, 0u};
      if (i < Mreal) {
        float4 v = x4[i];
        p.x = pack2(v.x, v.y);
        p.y = pack2(v.z, v.w);
      }
      xh2[i] = p;
    }
  } else {
    // pack weights to bf16 [128][128] row-major (combined l|r blocks)
    int idx = (blockIdx.x - 3072) * 256 + t;
    for (int i = idx; i < 128 * 128; i += 32 * 256) {
      int o = i >> 7, k = i & 127;
      w1h[i] = f2bf((k < 64) ? W1l[o * 64 + k] : W1r[o * 64 + (k - 64)]);
      w2h[i] = f2bf((o < 64) ? W2l[o * 128 + k] : W2r[(o - 64) * 128 + k]);
    }
  }
}

// ======== scan: ebuf chunked-region starts + padded csr starts ========
__global__ __launch_bounds__(256) void k_bscan(const int* __restrict__ bh,
                                               int* __restrict__ bstart,
                                               int* __restrict__ rstart,
                                               int* __restrict__ gcur) {
  __shared__ int s1[NBK], s2[NBK];
  int t = threadIdx.x;
  int cnt = bh[t * GS];
  int region = 16 * min(cnt, (cnt >> 4) + 512);
  int creg = cnt + 4096;  // rows 8-padded: <= 7 pad slots per row * 512 rows
  s1[t] = region; s2[t] = creg;
  __syncthreads();
  for (int off = 1; off < NBK; off <<= 1) {
    int a1 = (t >= off) ? s1[t - off] : 0;
    int a2 = (t >= off) ? s2[t - off] : 0;
    __syncthreads();
    s1[t] += a1; s2[t] += a2;
    __syncthreads();
  }
  int ex1 = s1[t] - region;
  int ex2 = s2[t] - creg;
  bstart[t] = ex1; gcur[t * GS] = ex1; rstart[t] = ex2;
}

// ======== multisplit: transposed ring bins, line-padded cursors, 8-fetch ====
__global__ __launch_bounds__(256) void k_msplit(const int* __restrict__ src,
                                                const int* __restrict__ dst,
                                                int* __restrict__ gcur,
                                                int* __restrict__ ebuf, int E) {
  __shared__ int bcnt[NBK], bhead[NBK];
  __shared__ int bins[BD][NBK];
  int t = threadIdx.x;
  bcnt[t] = 0; bhead[t] = 0;
  int per = (E + gridDim.x - 1) / gridDim.x;
  int e0 = blockIdx.x * per, e1 = min(E, e0 + per);
  int e = e0 + t;
  int pb[8], pv[8]; int pc = 0;
  __syncthreads();
  for (;;) {
    while (pc < 8 && e < e1) {
      int d = dst[e], s = src[e];
      pb[pc] = d >> 9; pv[pc] = (s << 9) | (d & 511);
      pc++; e += 256;
    }
    for (int q = pc - 1; q >= 0; --q) {
      int pos = atomicAdd(&bcnt[pb[q]], 1);
      if (pos < BD) {
        bins[(bhead[pb[q]] + pos) & (BD - 1)][pb[q]] = pv[q];
        pc--;
        if (q != pc) { pb[q] = pb[pc]; pv[q] = pv[pc]; }
      }
    }
    int pending = __syncthreads_count(pc > 0 || e < e1);
    int cntv = min(bcnt[t], BD);
    int head = bhead[t];
    while (cntv >= 16) {
      int base = atomicAdd(&gcur[t * GS], 16);
      int4 o[4];
#pragma unroll
      for (int k = 0; k < 16; ++k)
        ((int*)o)[k] = bins[(head + k) & (BD - 1)][t];
      int4* g = (int4*)(ebuf + base);
      g[0] = o[0]; g[1] = o[1]; g[2] = o[2]; g[3] = o[3];
      head = (head + 16) & (BD - 1);
      cntv -= 16;
    }
    bhead[t] = head;
    bcnt[t] = cntv;
    __syncthreads();
    if (!pending) break;
  }
  int cntv = bcnt[t];
  if (cntv > 0) {
    int head = bhead[t];
    int base = atomicAdd(&gcur[t * GS], 16);
#pragma unroll
    for (int k = 0; k < 16; ++k)
      ebuf[base + k] = (k < cntv) ? bins[(head + k) & (BD - 1)][t] : -1;
  }
}

// ======== per-bucket local CSR (512 nodes/bucket), 8-padded rows ========
__global__ __launch_bounds__(512) void k_localcsr(const int* __restrict__ ebuf,
                                                  const int* __restrict__ bstart,
                                                  const int* __restrict__ gcur,
                                                  const int* __restrict__ rstart,
                                                  int* __restrict__ csr,
                                                  int* __restrict__ row_start,
                                                  int* __restrict__ rend,
                                                  float* __restrict__ invd, int N) {
  __shared__ int lcnt[512], loff[512], lcur[512];
  int t = threadIdx.x, b = blockIdx.x;
  int start = bstart[b], endp = gcur[b * GS], rs = rstart[b];
  lcnt[t] = 0;
  __syncthreads();
  for (int i = start + t; i < endp; i += 512) {
    int pe = ebuf[i];
    if (pe != -1) atomicAdd(&lcnt[pe & 511], 1);
  }
  __syncthreads();
  int v = lcnt[t];
  int pvn = (v + 7) & ~7;
  loff[t] = pvn;
  __syncthreads();
  for (int off = 1; off < 512; off <<= 1) {
    int a = (t >= off) ? loff[t - off] : 0;
    __syncthreads();
    loff[t] += a;
    __syncthreads();
  }
  int ex = loff[t] - pvn;
  lcur[t] = ex;
  int node = (b << 9) + t;
  if (node < N) {
    row_start[node] = rs + ex;
    rend[node] = rs + ex + pvn;
    invd[node] = 1.0f / fmaxf((float)v, 1.0f);
  }
  __syncthreads();
  for (int i = start + t; i < endp; i += 512) {
    int pe = ebuf[i];
    if (pe != -1) {
      int pos = atomicAdd(&lcur[pe & 511], 1);
      csr[rs + pos] = pe >> 9;
    }
  }
  for (int k = ex + v; k < ex + pvn; ++k) csr[rs + k] = N;
}

// ======== FUSED gather1 + lin1 + lin2: one kernel, 64 nodes/block ========
// 512 thr. Phase G: 8 lanes/node padded gather with csr-index software
// pipeline; all loop-independent loads (weight frags, biases, self-x row)
// issued BEFORE the gather so they fly under it. Then round-9 lin12 verbatim.
__global__ __launch_bounds__(512, 6) void k_glin(
    const uint4* __restrict__ xh4, const int* __restrict__ csr,
    const int* __restrict__ row_start, const int* __restrict__ rend,
    const float* __restrict__ invd,
    const unsigned short* __restrict__ w1h, const unsigned short* __restrict__ w2h,
    const float* __restrict__ b1, const float* __restrict__ b2,
    uint4* __restrict__ zh4, float* __restrict__ r, int N) {
  __shared__ __align__(16) unsigned short sA[64 * 136];  // [agg|x] rows; reused as sZ [64][72]
  __shared__ __align__(16) unsigned short sH[64 * 136];  // h handoff; reused as sR [64][68] f32
  int t = threadIdx.x;
  if (blockIdx.x == 0 && t < 8) zh4[N * 8 + t] = (uint4){0u, 0u, 0u, 0u};  // dummy row
  int base = (int)blockIdx.x << 6;
  int w = t >> 6, lane = t & 63, qm = lane >> 4, ln = lane & 15;
  int o = w * 16 + ln;

  // ---- hoisted loop-independent loads: issue NOW, consume after gather ----
  bf16x8 w1f[4], w2f[4];
#pragma unroll
  for (int kc = 0; kc < 4; ++kc) {
    w1f[kc] = *(const bf16x8*)(w1h + o * 128 + kc * 32 + qm * 8);
    w2f[kc] = *(const bf16x8*)(w2h + o * 128 + kc * 32 + qm * 8);
  }
  float4 b1v = *(const float4*)(b1 + w * 16 + qm * 4);
  int u = w * 16 + qm * 4;
  float4 b2v = {0.f, 0.f, 0.f, 0.f};
  if (u >= 64) b2v = *(const float4*)(b2 + (u - 64));

  // ---- phase G: gather agg into regs, stage [agg|x] into sA ----
  {
    int nl = t >> 3;            // node_local 0..63
    int node = base + nl;
    int c = t & 7;              // channel quad
    int lb = t & 56;            // 8-lane group base within wave
    uint4 xv = {0u, 0u, 0u, 0u};
    if (node < N) xv = xh4[node * 8 + c];   // self row: issue early
    int j = 0, end = 0;
    float inv = 0.f;
    if (node < N) { j = row_start[node]; end = rend[node]; inv = invd[node]; }
    float a0 = 0, a1 = 0, a2 = 0, a3 = 0, a4 = 0, a5 = 0, a6 = 0, a7 = 0;
    if (j < end) {
      int sv = csr[j + c];      // prologue index load
      for (; j < end; j += 8) {
        // prefetch next chunk's indices (safe: >=512-int slack per bucket
        // region, so the j+8..j+15 overrun on the last chunk stays in-buffer)
        int svn = csr[j + 8 + c];
#pragma unroll
        for (int k = 0; k < 8; ++k) {
          int s = __shfl(sv, lb + k);
          uint4 v = xh4[s * 8 + c];  // dummy src = N -> zero row
          a0 += bf2f(v.x & 0xffffu); a1 += bf2f(v.x >> 16);
          a2 += bf2f(v.y & 0xffffu); a3 += bf2f(v.y >> 16);
          a4 += bf2f(v.z & 0xffffu); a5 += bf2f(v.z >> 16);
          a6 += bf2f(v.w & 0xffffu); a7 += bf2f(v.w >> 16);
        }
        sv = svn;
      }
    }
    uint4 pa;
    pa.x = pack2(a0 * inv, a1 * inv);
    pa.y = pack2(a2 * inv, a3 * inv);
    pa.z = pack2(a4 * inv, a5 * inv);
    pa.w = pack2(a6 * inv, a7 * inv);
    *(uint4*)(sA + nl * 136 + c * 8) = pa;               // k 0..63  = agg
    *(uint4*)(sA + nl * 136 + 64 + c * 8) = xv;          // k 64..127 = x
  }
  __syncthreads();

  // ---- lin1: sA frags, MFMA, relu -> sH ----
#pragma unroll
  for (int g = 0; g < 4; ++g) {
    int row = g * 16 + ln;
    bf16x8 af[4];
#pragma unroll
    for (int kc = 0; kc < 4; ++kc)
      af[kc] = *(const bf16x8*)(sA + row * 136 + kc * 32 + qm * 8);
    f32x4 acc = {0.f, 0.f, 0.f, 0.f};
#pragma unroll
    for (int kc = 0; kc < 4; ++kc)
      acc = __builtin_amdgcn_mfma_f32_16x16x32_bf16(w1f[kc], af[kc], acc, 0, 0, 0);
    uint2 hp;
    hp.x = pack2(fmaxf(acc[0] + b1v.x, 0.f), fmaxf(acc[1] + b1v.y, 0.f));
    hp.y = pack2(fmaxf(acc[2] + b1v.z, 0.f), fmaxf(acc[3] + b1v.w, 0.f));
    *(uint2*)(sH + row * 136 + w * 16 + qm * 4) = hp;
  }
  __syncthreads();
  // ---- lin2 compute: results held in registers ----
  f32x4 pg[4];
#pragma unroll
  for (int g = 0; g < 4; ++g) {
    int row = g * 16 + ln;
    bf16x8 hf[4];
#pragma unroll
    for (int kc = 0; kc < 4; ++kc)
      hf[kc] = *(const bf16x8*)(sH + row * 136 + kc * 32 + qm * 8);
    f32x4 acc = {0.f, 0.f, 0.f, 0.f};
#pragma unroll
    for (int kc = 0; kc < 4; ++kc)
      acc = __builtin_amdgcn_mfma_f32_16x16x32_bf16(w2f[kc], hf[kc], acc, 0, 0, 0);
    pg[g] = acc;
  }
  __syncthreads();  // sA+sH reads done; reuse as sZ / sR
  // ---- epilogue transpose: z (waves 0-3) and r (waves 4-7) concurrently ----
  unsigned short* sZ = sA;   // [64][72] ushort
  float* sR = (float*)sH;    // [64][68] float
  if (w < 4) {
#pragma unroll
    for (int g = 0; g < 4; ++g) {
      int row = g * 16 + ln;
      uint2 zv;
      zv.x = pack2(pg[g][0], pg[g][1]);
      zv.y = pack2(pg[g][2], pg[g][3]);
      *(uint2*)(sZ + row * 72 + u) = zv;
    }
  } else {
#pragma unroll
    for (int g = 0; g < 4; ++g) {
      int row = g * 16 + ln;
      f32x4 rv;
      rv.x = pg[g][0] + b2v.x; rv.y = pg[g][1] + b2v.y;
      rv.z = pg[g][2] + b2v.z; rv.w = pg[g][3] + b2v.w;
      *(f32x4*)(sR + row * 68 + (u - 64)) = rv;
    }
  }
  __syncthreads();
  {  // coalesced zh store: 64 rows x 128B, one pass
    int row = t >> 3, ch = t & 7;
    int node = base + row;
    uint4 zv = *(const uint4*)(sZ + row * 72 + ch * 8);
    if (node < N) zh4[node * 8 + ch] = zv;
  }
#pragma unroll
  for (int k = 0; k < 2; ++k) {  // coalesced r store: 64 rows x 256B
    int i = k * 512 + t;
    int row = i >> 4, ch = i & 15;
    int node = base + row;
    f32x4 rv = *(const f32x4*)(sR + row * 68 + ch * 4);
    if (node < N)
      *(f32x4*)(r + (size_t)node * 64 + ch * 4) = rv;  // re-read by gather2b: keep cached
  }
}

// ======== gather 2: csr-pipelined, hoisted r loads, fused sigmoid ========
__global__ __launch_bounds__(256) void k_gather2b(const uint4* __restrict__ zh4,
                                                  const float* __restrict__ r,
                                                  const int* __restrict__ csr,
                                                  const int* __restrict__ row_start,
                                                  const int* __restrict__ rend,
                                                  const float* __restrict__ invd,
                                                  float* __restrict__ out, int N) {
  int node = (blockIdx.x * 256 + threadIdx.x) >> 3;
  if (node >= N) return;
  int c = threadIdx.x & 7;
  int lb = threadIdx.x & 56;
  // hoisted loop-independent loads: fly under the gather
  const f32x4* r4 = (const f32x4*)r;
  int bi = node * 16 + c * 2;  // f32x4 units; lane covers channels 8c..8c+7
  f32x4 r0 = r4[bi];           // L2/L3-warm from k_glin
  f32x4 r1 = r4[bi + 1];
  float inv = invd[node];
  int j = row_start[node], end = rend[node];  // padded end
  float a0 = 0, a1 = 0, a2 = 0, a3 = 0, a4 = 0, a5 = 0, a6 = 0, a7 = 0;
  if (j < end) {
    int sv = csr[j + c];
    for (; j < end; j += 8) {
      int svn = csr[j + 8 + c];  // safe: bucket-region slack >= 512 ints
#pragma unroll
      for (int k = 0; k < 8; ++k) {
        int s = __shfl(sv, lb + k);
        uint4 v = zh4[s * 8 + c];   // dummy src = N -> zero row
        a0 += bf2f(v.x & 0xffffu); a1 += bf2f(v.x >> 16);
        a2 += bf2f(v.y & 0xffffu); a3 += bf2f(v.y >> 16);
        a4 += bf2f(v.z & 0xffffu); a5 += bf2f(v.z >> 16);
        a6 += bf2f(v.w & 0xffffu); a7 += bf2f(v.w >> 16);
      }
      sv = svn;
    }
  }
  f32x4* o4 = (f32x4*)out;
  f32x4 w0, w1;
  w0.x = 1.0f / (1.0f + __expf(-(a0 * inv + r0.x)));
  w0.y = 1.0f / (1.0f + __expf(-(a1 * inv + r0.y)));
  w0.z = 1.0f / (1.0f + __expf(-(a2 * inv + r0.z)));
  w0.w = 1.0f / (1.0f + __expf(-(a3 * inv + r0.w)));
  w1.x = 1.0f / (1.0f + __expf(-(a4 * inv + r1.x)));
  w1.y = 1.0f / (1.0f + __expf(-(a5 * inv + r1.y)));
  w1.z = 1.0f / (1.0f + __expf(-(a6 * inv + r1.z)));
  w1.w = 1.0f / (1.0f + __expf(-(a7 * inv + r1.w)));
  __builtin_nontemporal_store(w0, &o4[bi]);             // never re-read
  __builtin_nontemporal_store(w1, &o4[bi + 1]);
}

extern "C" void kernel_launch(void* const* d_in, const int* in_sizes, int n_in,
                              void* d_out, int out_size, void* d_ws, size_t ws_size,
                              hipStream_t stream) {
  const float* x   = (const float*)d_in[0];
  const int*   ei  = (const int*)d_in[1];
  const float* W1l = (const float*)d_in[2];
  const float* W1r = (const float*)d_in[3];
  const float* b1  = (const float*)d_in[4];
  const float* W2l = (const float*)d_in[5];
  const float* W2r = (const float*)d_in[6];
  const float* b2  = (const float*)d_in[7];
  float* out = (float*)d_out;

  int N = in_sizes[0] / IN_C;
  int E = in_sizes[1] / 2;
  const int* src = ei;
  const int* dst = ei + E;

  // ws: [bh 256*GS][gcur 256*GS][bstart 256][rstart 256][csr E+256*4096]
  //     [row_start N][rend N][invd N][w1h 128x128 bf16][w2h 128x128 bf16]
  //     [xh (N+1)*64 bf16][zh (N+1)*64 bf16][r N*64 f]
  //     (ebuf aliases zh+r: ~38.5MB >= 14.8MB worst-case; dead before
  //      k_glin writes them)
  char* ws = (char*)d_ws;
  size_t off = 0;
  auto alignup = [](size_t v) { return (v + 511) & ~(size_t)511; };
  int* bh = (int*)(ws + off);         off = alignup(off + NBK * GS * 4);
  int* gcur = (int*)(ws + off);       off = alignup(off + NBK * GS * 4);
  int* bstart = (int*)(ws + off);     off = alignup(off + NBK * 4);
  int* rstart = (int*)(ws + off);     off = alignup(off + NBK * 4);
  int* csr = (int*)(ws + off);        off = alignup(off + ((size_t)E + NBK * 4096) * 4);
  int* row_start = (int*)(ws + off);  off = alignup(off + (size_t)N * 4);
  int* rend = (int*)(ws + off);       off = alignup(off + (size_t)N * 4);
  float* invd = (float*)(ws + off);   off = alignup(off + (size_t)N * 4);
  unsigned short* w1h = (unsigned short*)(ws + off);  off = alignup(off + 128 * 128 * 2);
  unsigned short* w2h = (unsigned short*)(ws + off);  off = alignup(off + 128 * 128 * 2);
  unsigned short* xh = (unsigned short*)(ws + off);   off = alignup(off + (size_t)(N + 1) * 64 * 2);
  unsigned short* zh = (unsigned short*)(ws + off);   off = alignup(off + (size_t)(N + 1) * 64 * 2);
  float* rbuf = (float*)(ws + off);   off = alignup(off + (size_t)N * 64 * 4);
  int* ebuf = (int*)zh;  // spans zh+r (~38.5MB >= 14.8MB worst-case region);
                         // dead before k_glin writes zh/r

  hipMemsetAsync(bh, 0, NBK * GS * 4, stream);
  k_xb<<<3104, 256, 0, stream>>>(dst, bh, (const float4*)x, (uint2*)xh,
                                 W1l, W1r, W2l, W2r, w1h, w2h,
                                 E, N * 16, (N + 1) * 16);
  k_bscan<<<1, NBK, 0, stream>>>(bh, bstart, rstart, gcur);
  k_msplit<<<512, 256, 0, stream>>>(src, dst, gcur, ebuf, E);
  k_localcsr<<<NBK, 512, 0, stream>>>(ebuf, bstart, gcur, rstart, csr,
                                      row_start, rend, invd, N);

  k_glin<<<(N + 63) / 64, 512, 0, stream>>>((const uint4*)xh, csr, row_start,
                                            rend, invd, w1h, w2h, b1, b2,
                                            (uint4*)zh, rbuf, N);
  k_gather2b<<<(N + 31) / 32, 256, 0, stream>>>((const uint4*)zh, rbuf, csr,
                                                row_start, rend, invd, out, N);
}

// Round 12
// 255.486 us; speedup vs baseline: 1.0611x; 1.0611x over previous
//
#include <hip/hip_runtime.h>
#include <math.h>

#define IN_C 64
#define HID_C 128
#define OUT_C 64
#define NBK 256   // buckets of 512 nodes: bucket = dst >> 9
#define BD 64     // msplit bin ring depth
#define GS 16     // global atomic counter stride (ints) -> one 64B line each
// packed edge = (src<<9)|(dst&511); sentinel -1 unreachable (src <= N < 2^17).
// CSR rows padded to 8-multiples with dummy src = N (row N of xh/zh zeroed).
// Gathers: 8 lanes/node, unguarded padded loop + csr-index software pipeline
// ONLY (no cross-loop hoists: r11's hoisted weights spilled to scratch).

typedef __attribute__((ext_vector_type(8))) short bf16x8;   // 8 bf16 (4 VGPRs)
typedef __attribute__((ext_vector_type(4))) float f32x4;    // mfma C/D, NT-able
typedef __attribute__((ext_vector_type(4))) unsigned u32x4; // NT-able uint4

__device__ __forceinline__ unsigned short f2bf(float f) {
  unsigned u = __float_as_uint(f);
  u = (u + 0x7FFFu + ((u >> 16) & 1u)) >> 16;  // RNE
  return (unsigned short)u;
}
__device__ __forceinline__ float bf2f(unsigned v) {  // low 16 bits = bf16
  return __uint_as_float(v << 16);
}
__device__ __forceinline__ unsigned pack2(float a, float b) {
  return (unsigned)f2bf(a) | ((unsigned)f2bf(b) << 16);
}

// ==== fused: bhist (0..1023) + x->bf16 cast (1024..3071) + W pack (3072+) ====
__global__ __launch_bounds__(256) void k_xb(const int* __restrict__ dst,
                                            int* __restrict__ bh,
                                            const float4* __restrict__ x4,
                                            uint2* __restrict__ xh2,
                                            const float* __restrict__ W1l,
                                            const float* __restrict__ W1r,
                                            const float* __restrict__ W2l,
                                            const float* __restrict__ W2r,
                                            unsigned short* __restrict__ w1h,
                                            unsigned short* __restrict__ w2h,
                                            int E, int Mreal, int Mtot) {
  __shared__ int hh[NBK];
  int t = threadIdx.x;
  if (blockIdx.x < 1024) {
    hh[t] = 0;
    __syncthreads();
    for (int e = blockIdx.x * 256 + t; e < E; e += 1024 * 256)
      atomicAdd(&hh[dst[e] >> 9], 1);
    __syncthreads();
    if (hh[t]) atomicAdd(&bh[t * GS], hh[t]);
  } else if (blockIdx.x < 3072) {
    int b = blockIdx.x - 1024;
    for (int i = b * 256 + t; i < Mtot; i += 2048 * 256) {
      uint2 p = {0u, 0u};
      if (i < Mreal) {
        float4 v = x4[i];
        p.x = pack2(v.x, v.y);
        p.y = pack2(v.z, v.w);
      }
      xh2[i] = p;
    }
  } else {
    // pack weights to bf16 [128][128] row-major (combined l|r blocks)
    int idx = (blockIdx.x - 3072) * 256 + t;
    for (int i = idx; i < 128 * 128; i += 32 * 256) {
      int o = i >> 7, k = i & 127;
      w1h[i] = f2bf((k < 64) ? W1l[o * 64 + k] : W1r[o * 64 + (k - 64)]);
      w2h[i] = f2bf((o < 64) ? W2l[o * 128 + k] : W2r[(o - 64) * 128 + k]);
    }
  }
}

// ======== scan: ebuf chunked-region starts + padded csr starts ========
__global__ __launch_bounds__(256) void k_bscan(const int* __restrict__ bh,
                                               int* __restrict__ bstart,
                                               int* __restrict__ rstart,
                                               int* __restrict__ gcur) {
  __shared__ int s1[NBK], s2[NBK];
  int t = threadIdx.x;
  int cnt = bh[t * GS];
  int region = 16 * min(cnt, (cnt >> 4) + 512);
  int creg = cnt + 4096;  // rows 8-padded: <= 7 pad slots per row * 512 rows
  s1[t] = region; s2[t] = creg;
  __syncthreads();
  for (int off = 1; off < NBK; off <<= 1) {
    int a1 = (t >= off) ? s1[t - off] : 0;
    int a2 = (t >= off) ? s2[t - off] : 0;
    __syncthreads();
    s1[t] += a1; s2[t] += a2;
    __syncthreads();
  }
  int ex1 = s1[t] - region;
  int ex2 = s2[t] - creg;
  bstart[t] = ex1; gcur[t * GS] = ex1; rstart[t] = ex2;
}

// ======== multisplit: transposed ring bins, line-padded cursors, 8-fetch ====
__global__ __launch_bounds__(256) void k_msplit(const int* __restrict__ src,
                                                const int* __restrict__ dst,
                                                int* __restrict__ gcur,
                                                int* __restrict__ ebuf, int E) {
  __shared__ int bcnt[NBK], bhead[NBK];
  __shared__ int bins[BD][NBK];
  int t = threadIdx.x;
  bcnt[t] = 0; bhead[t] = 0;
  int per = (E + gridDim.x - 1) / gridDim.x;
  int e0 = blockIdx.x * per, e1 = min(E, e0 + per);
  int e = e0 + t;
  int pb[8], pv[8]; int pc = 0;
  __syncthreads();
  for (;;) {
    while (pc < 8 && e < e1) {
      int d = dst[e], s = src[e];
      pb[pc] = d >> 9; pv[pc] = (s << 9) | (d & 511);
      pc++; e += 256;
    }
    for (int q = pc - 1; q >= 0; --q) {
      int pos = atomicAdd(&bcnt[pb[q]], 1);
      if (pos < BD) {
        bins[(bhead[pb[q]] + pos) & (BD - 1)][pb[q]] = pv[q];
        pc--;
        if (q != pc) { pb[q] = pb[pc]; pv[q] = pv[pc]; }
      }
    }
    int pending = __syncthreads_count(pc > 0 || e < e1);
    int cntv = min(bcnt[t], BD);
    int head = bhead[t];
    while (cntv >= 16) {
      int base = atomicAdd(&gcur[t * GS], 16);
      int4 o[4];
#pragma unroll
      for (int k = 0; k < 16; ++k)
        ((int*)o)[k] = bins[(head + k) & (BD - 1)][t];
      int4* g = (int4*)(ebuf + base);
      g[0] = o[0]; g[1] = o[1]; g[2] = o[2]; g[3] = o[3];
      head = (head + 16) & (BD - 1);
      cntv -= 16;
    }
    bhead[t] = head;
    bcnt[t] = cntv;
    __syncthreads();
    if (!pending) break;
  }
  int cntv = bcnt[t];
  if (cntv > 0) {
    int head = bhead[t];
    int base = atomicAdd(&gcur[t * GS], 16);
#pragma unroll
    for (int k = 0; k < 16; ++k)
      ebuf[base + k] = (k < cntv) ? bins[(head + k) & (BD - 1)][t] : -1;
  }
}

// ======== per-bucket local CSR (512 nodes/bucket), 8-padded rows ========
__global__ __launch_bounds__(512) void k_localcsr(const int* __restrict__ ebuf,
                                                  const int* __restrict__ bstart,
                                                  const int* __restrict__ gcur,
                                                  const int* __restrict__ rstart,
                                                  int* __restrict__ csr,
                                                  int* __restrict__ row_start,
                                                  int* __restrict__ rend,
                                                  float* __restrict__ invd, int N) {
  __shared__ int lcnt[512], loff[512], lcur[512];
  int t = threadIdx.x, b = blockIdx.x;
  int start = bstart[b], endp = gcur[b * GS], rs = rstart[b];
  lcnt[t] = 0;
  __syncthreads();
  for (int i = start + t; i < endp; i += 512) {
    int pe = ebuf[i];
    if (pe != -1) atomicAdd(&lcnt[pe & 511], 1);
  }
  __syncthreads();
  int v = lcnt[t];
  int pvn = (v + 7) & ~7;
  loff[t] = pvn;
  __syncthreads();
  for (int off = 1; off < 512; off <<= 1) {
    int a = (t >= off) ? loff[t - off] : 0;
    __syncthreads();
    loff[t] += a;
    __syncthreads();
  }
  int ex = loff[t] - pvn;
  lcur[t] = ex;
  int node = (b << 9) + t;
  if (node < N) {
    row_start[node] = rs + ex;
    rend[node] = rs + ex + pvn;
    invd[node] = 1.0f / fmaxf((float)v, 1.0f);
  }
  __syncthreads();
  for (int i = start + t; i < endp; i += 512) {
    int pe = ebuf[i];
    if (pe != -1) {
      int pos = atomicAdd(&lcur[pe & 511], 1);
      csr[rs + pos] = pe >> 9;
    }
  }
  for (int k = ex + v; k < ex + pvn; ++k) csr[rs + k] = N;
}

// ======== FUSED gather1 + lin1 + lin2: one kernel, 64 nodes/block ========
// 512 thr. Phase G: 8 lanes/node padded gather with csr-index software
// pipeline (ONLY loop-local state -- weights/biases load AFTER the gather so
// nothing heavy is live across it; r11's hoist spilled). Then r9 lin12.
__global__ __launch_bounds__(512, 6) void k_glin(
    const uint4* __restrict__ xh4, const int* __restrict__ csr,
    const int* __restrict__ row_start, const int* __restrict__ rend,
    const float* __restrict__ invd,
    const unsigned short* __restrict__ w1h, const unsigned short* __restrict__ w2h,
    const float* __restrict__ b1, const float* __restrict__ b2,
    uint4* __restrict__ zh4, float* __restrict__ r, int N) {
  __shared__ __align__(16) unsigned short sA[64 * 136];  // [agg|x] rows; reused as sZ [64][72]
  __shared__ __align__(16) unsigned short sH[64 * 136];  // h handoff; reused as sR [64][68] f32
  int t = threadIdx.x;
  if (blockIdx.x == 0 && t < 8) zh4[N * 8 + t] = (uint4){0u, 0u, 0u, 0u};  // dummy row
  int base = (int)blockIdx.x << 6;

  // ---- phase G: gather agg into regs, stage [agg|x] into sA ----
  {
    int nl = t >> 3;            // node_local 0..63
    int node = base + nl;
    int c = t & 7;              // channel quad
    int lb = t & 56;            // 8-lane group base within wave
    int j = 0, end = 0;
    float inv = 0.f;
    if (node < N) { j = row_start[node]; end = rend[node]; inv = invd[node]; }
    float a0 = 0, a1 = 0, a2 = 0, a3 = 0, a4 = 0, a5 = 0, a6 = 0, a7 = 0;
    if (j < end) {
      int sv = csr[j + c];      // prologue index load
      for (; j < end; j += 8) {
        // prefetch next chunk's indices (safe: >=512-int slack per bucket
        // csr region, so j+8..j+15 overrun on the last chunk stays in-buffer)
        int svn = csr[j + 8 + c];
#pragma unroll
        for (int k = 0; k < 8; ++k) {
          int s = __shfl(sv, lb + k);
          uint4 v = xh4[s * 8 + c];  // dummy src = N -> zero row
          a0 += bf2f(v.x & 0xffffu); a1 += bf2f(v.x >> 16);
          a2 += bf2f(v.y & 0xffffu); a3 += bf2f(v.y >> 16);
          a4 += bf2f(v.z & 0xffffu); a5 += bf2f(v.z >> 16);
          a6 += bf2f(v.w & 0xffffu); a7 += bf2f(v.w >> 16);
        }
        sv = svn;
      }
    }
    uint4 pa;
    pa.x = pack2(a0 * inv, a1 * inv);
    pa.y = pack2(a2 * inv, a3 * inv);
    pa.z = pack2(a4 * inv, a5 * inv);
    pa.w = pack2(a6 * inv, a7 * inv);
    *(uint4*)(sA + nl * 136 + c * 8) = pa;               // k 0..63  = agg
    uint4 xv = {0u, 0u, 0u, 0u};
    if (node < N) xv = xh4[node * 8 + c];
    *(uint4*)(sA + nl * 136 + 64 + c * 8) = xv;          // k 64..127 = x
  }

  // ---- weight fragments (L2-hot prepacked tables) + biases: AFTER gather ----
  int w = t >> 6, lane = t & 63, qm = lane >> 4, ln = lane & 15;
  int o = w * 16 + ln;
  bf16x8 w1f[4], w2f[4];
#pragma unroll
  for (int kc = 0; kc < 4; ++kc) {
    w1f[kc] = *(const bf16x8*)(w1h + o * 128 + kc * 32 + qm * 8);
    w2f[kc] = *(const bf16x8*)(w2h + o * 128 + kc * 32 + qm * 8);
  }
  float4 b1v = *(const float4*)(b1 + w * 16 + qm * 4);
  int u = w * 16 + qm * 4;
  float4 b2v = {0.f, 0.f, 0.f, 0.f};
  if (u >= 64) b2v = *(const float4*)(b2 + (u - 64));
  __syncthreads();

  // ---- lin1: sA frags, MFMA, relu -> sH ----
#pragma unroll
  for (int g = 0; g < 4; ++g) {
    int row = g * 16 + ln;
    bf16x8 af[4];
#pragma unroll
    for (int kc = 0; kc < 4; ++kc)
      af[kc] = *(const bf16x8*)(sA + row * 136 + kc * 32 + qm * 8);
    f32x4 acc = {0.f, 0.f, 0.f, 0.f};
#pragma unroll
    for (int kc = 0; kc < 4; ++kc)
      acc = __builtin_amdgcn_mfma_f32_16x16x32_bf16(w1f[kc], af[kc], acc, 0, 0, 0);
    uint2 hp;
    hp.x = pack2(fmaxf(acc[0] + b1v.x, 0.f), fmaxf(acc[1] + b1v.y, 0.f));
    hp.y = pack2(fmaxf(acc[2] + b1v.z, 0.f), fmaxf(acc[3] + b1v.w, 0.f));
    *(uint2*)(sH + row * 136 + w * 16 + qm * 4) = hp;
  }
  __syncthreads();
  // ---- lin2 compute: results held in registers ----
  f32x4 pg[4];
#pragma unroll
  for (int g = 0; g < 4; ++g) {
    int row = g * 16 + ln;
    bf16x8 hf[4];
#pragma unroll
    for (int kc = 0; kc < 4; ++kc)
      hf[kc] = *(const bf16x8*)(sH + row * 136 + kc * 32 + qm * 8);
    f32x4 acc = {0.f, 0.f, 0.f, 0.f};
#pragma unroll
    for (int kc = 0; kc < 4; ++kc)
      acc = __builtin_amdgcn_mfma_f32_16x16x32_bf16(w2f[kc], hf[kc], acc, 0, 0, 0);
    pg[g] = acc;
  }
  __syncthreads();  // sA+sH reads done; reuse as sZ / sR
  // ---- epilogue transpose: z (waves 0-3) and r (waves 4-7) concurrently ----
  unsigned short* sZ = sA;   // [64][72] ushort
  float* sR = (float*)sH;    // [64][68] float
  if (w < 4) {
#pragma unroll
    for (int g = 0; g < 4; ++g) {
      int row = g * 16 + ln;
      uint2 zv;
      zv.x = pack2(pg[g][0], pg[g][1]);
      zv.y = pack2(pg[g][2], pg[g][3]);
      *(uint2*)(sZ + row * 72 + u) = zv;
    }
  } else {
#pragma unroll
    for (int g = 0; g < 4; ++g) {
      int row = g * 16 + ln;
      f32x4 rv;
      rv.x = pg[g][0] + b2v.x; rv.y = pg[g][1] + b2v.y;
      rv.z = pg[g][2] + b2v.z; rv.w = pg[g][3] + b2v.w;
      *(f32x4*)(sR + row * 68 + (u - 64)) = rv;
    }
  }
  __syncthreads();
  {  // coalesced zh store: 64 rows x 128B, one pass
    int row = t >> 3, ch = t & 7;
    int node = base + row;
    uint4 zv = *(const uint4*)(sZ + row * 72 + ch * 8);
    if (node < N) zh4[node * 8 + ch] = zv;
  }
#pragma unroll
  for (int k = 0; k < 2; ++k) {  // coalesced r store: 64 rows x 256B
    int i = k * 512 + t;
    int row = i >> 4, ch = i & 15;
    int node = base + row;
    f32x4 rv = *(const f32x4*)(sR + row * 68 + ch * 4);
    if (node < N)
      *(f32x4*)(r + (size_t)node * 64 + ch * 4) = rv;  // re-read by gather2b: keep cached
  }
}

// ======== gather 2: csr-pipelined (no hoists), fused sigmoid epilogue ======
__global__ __launch_bounds__(256) void k_gather2b(const uint4* __restrict__ zh4,
                                                  const float* __restrict__ r,
                                                  const int* __restrict__ csr,
                                                  const int* __restrict__ row_start,
                                                  const int* __restrict__ rend,
                                                  const float* __restrict__ invd,
                                                  float* __restrict__ out, int N) {
  int node = (blockIdx.x * 256 + threadIdx.x) >> 3;
  if (node >= N) return;
  int c = threadIdx.x & 7;
  int lb = threadIdx.x & 56;
  int j = row_start[node], end = rend[node];  // padded end
  float a0 = 0, a1 = 0, a2 = 0, a3 = 0, a4 = 0, a5 = 0, a6 = 0, a7 = 0;
  if (j < end) {
    int sv = csr[j + c];
    for (; j < end; j += 8) {
      int svn = csr[j + 8 + c];  // safe: bucket-region slack >= 512 ints
#pragma unroll
      for (int k = 0; k < 8; ++k) {
        int s = __shfl(sv, lb + k);
        uint4 v = zh4[s * 8 + c];   // dummy src = N -> zero row
        a0 += bf2f(v.x & 0xffffu); a1 += bf2f(v.x >> 16);
        a2 += bf2f(v.y & 0xffffu); a3 += bf2f(v.y >> 16);
        a4 += bf2f(v.z & 0xffffu); a5 += bf2f(v.z >> 16);
        a6 += bf2f(v.w & 0xffffu); a7 += bf2f(v.w >> 16);
      }
      sv = svn;
    }
  }
  float inv = invd[node];
  const f32x4* r4 = (const f32x4*)r;
  f32x4* o4 = (f32x4*)out;
  int bi = node * 16 + c * 2;  // f32x4 units; lane covers channels 8c..8c+7
  f32x4 r0 = r4[bi];           // L2/L3-warm from k_glin
  f32x4 r1 = r4[bi + 1];
  f32x4 w0, w1;
  w0.x = 1.0f / (1.0f + __expf(-(a0 * inv + r0.x)));
  w0.y = 1.0f / (1.0f + __expf(-(a1 * inv + r0.y)));
  w0.z = 1.0f / (1.0f + __expf(-(a2 * inv + r0.z)));
  w0.w = 1.0f / (1.0f + __expf(-(a3 * inv + r0.w)));
  w1.x = 1.0f / (1.0f + __expf(-(a4 * inv + r1.x)));
  w1.y = 1.0f / (1.0f + __expf(-(a5 * inv + r1.y)));
  w1.z = 1.0f / (1.0f + __expf(-(a6 * inv + r1.z)));
  w1.w = 1.0f / (1.0f + __expf(-(a7 * inv + r1.w)));
  __builtin_nontemporal_store(w0, &o4[bi]);             // never re-read
  __builtin_nontemporal_store(w1, &o4[bi + 1]);
}

extern "C" void kernel_launch(void* const* d_in, const int* in_sizes, int n_in,
                              void* d_out, int out_size, void* d_ws, size_t ws_size,
                              hipStream_t stream) {
  const float* x   = (const float*)d_in[0];
  const int*   ei  = (const int*)d_in[1];
  const float* W1l = (const float*)d_in[2];
  const float* W1r = (const float*)d_in[3];
  const float* b1  = (const float*)d_in[4];
  const float* W2l = (const float*)d_in[5];
  const float* W2r = (const float*)d_in[6];
  const float* b2  = (const float*)d_in[7];
  float* out = (float*)d_out;

  int N = in_sizes[0] / IN_C;
  int E = in_sizes[1] / 2;
  const int* src = ei;
  const int* dst = ei + E;

  // ws: [bh 256*GS][gcur 256*GS][bstart 256][rstart 256][csr E+256*4096]
  //     [row_start N][rend N][invd N][w1h 128x128 bf16][w2h 128x128 bf16]
  //     [xh (N+1)*64 bf16][zh (N+1)*64 bf16][r N*64 f]
  //     (ebuf aliases zh+r: ~38.5MB >= 14.8MB worst-case; dead before
  //      k_glin writes them)
  char* ws = (char*)d_ws;
  size_t off = 0;
  auto alignup = [](size_t v) { return (v + 511) & ~(size_t)511; };
  int* bh = (int*)(ws + off);         off = alignup(off + NBK * GS * 4);
  int* gcur = (int*)(ws + off);       off = alignup(off + NBK * GS * 4);
  int* bstart = (int*)(ws + off);     off = alignup(off + NBK * 4);
  int* rstart = (int*)(ws + off);     off = alignup(off + NBK * 4);
  int* csr = (int*)(ws + off);        off = alignup(off + ((size_t)E + NBK * 4096) * 4);
  int* row_start = (int*)(ws + off);  off = alignup(off + (size_t)N * 4);
  int* rend = (int*)(ws + off);       off = alignup(off + (size_t)N * 4);
  float* invd = (float*)(ws + off);   off = alignup(off + (size_t)N * 4);
  unsigned short* w1h = (unsigned short*)(ws + off);  off = alignup(off + 128 * 128 * 2);
  unsigned short* w2h = (unsigned short*)(ws + off);  off = alignup(off + 128 * 128 * 2);
  unsigned short* xh = (unsigned short*)(ws + off);   off = alignup(off + (size_t)(N + 1) * 64 * 2);
  unsigned short* zh = (unsigned short*)(ws + off);   off = alignup(off + (size_t)(N + 1) * 64 * 2);
  float* rbuf = (float*)(ws + off);   off = alignup(off + (size_t)N * 64 * 4);
  int* ebuf = (int*)zh;  // spans zh+r (~38.5MB >= 14.8MB worst-case region);
                         // dead before k_glin writes zh/r

  hipMemsetAsync(bh, 0, NBK * GS * 4, stream);
  k_xb<<<3104, 256, 0, stream>>>(dst, bh, (const float4*)x, (uint2*)xh,
                                 W1l, W1r, W2l, W2r, w1h, w2h,
                                 E, N * 16, (N + 1) * 16);
  k_bscan<<<1, NBK, 0, stream>>>(bh, bstart, rstart, gcur);
  k_msplit<<<512, 256, 0, stream>>>(src, dst, gcur, ebuf, E);
  k_localcsr<<<NBK, 512, 0, stream>>>(ebuf, bstart, gcur, rstart, csr,
                                      row_start, rend, invd, N);

  k_glin<<<(N + 63) / 64, 512, 0, stream>>>((const uint4*)xh, csr, row_start,
                                            rend, invd, w1h, w2h, b1, b2,
                                            (uint4*)zh, rbuf, N);
  k_gather2b<<<(N + 31) / 32, 256, 0, stream>>>((const uint4*)zh, rbuf, csr,
                                                row_start, rend, invd, out, N);
}